// Round 5
// baseline (494.303 us; speedup 1.0000x reference)
//
#include <hip/hip_runtime.h>

#define T_   256
#define F_   32
#define NBB  16     // batch elements per block
#define TPB  1024   // 16 waves, 4 per SIMD
#define IMW  104    // img row width in ushorts
#define PR1  260    // pre1 row stride (floats) per batch: 256 rows + pad, %32==4 -> 2-way max
#define PR2  132    // pre2 row stride (floats) per batch: 128 rows + pad

typedef __attribute__((ext_vector_type(8))) short bf16x8;
typedef __attribute__((ext_vector_type(4))) float f32x4;

__device__ __forceinline__ float sigmoid_fast(float x){ return __fdividef(1.f, 1.f + __expf(-x)); }
__device__ __forceinline__ float tanh_fast(float x){ float e = __expf(2.f*x); return 1.f - __fdividef(2.f, e + 1.f); }

__device__ __forceinline__ unsigned short bf16_rne(float x){
    unsigned u = __float_as_uint(x);
    u += 0x7FFF + ((u >> 16) & 1);
    return (unsigned short)(u >> 16);
}
__device__ __forceinline__ void bf16_split(float x, unsigned short& h, unsigned short& l){
    h = bf16_rne(x);
    float xr = __uint_as_float(((unsigned)h) << 16);
    l = bf16_rne(x - xr);
}

__device__ __forceinline__ void make_frags(const float* __restrict__ p8, bf16x8& fh, bf16x8& fl){
    #pragma unroll
    for (int e = 0; e < 8; ++e){
        unsigned short h, l; bf16_split(p8[e], h, l);
        fh[e] = (short)h; fl[e] = (short)l;
    }
}

#define MFMA(A,B,C) __builtin_amdgcn_mfma_f32_16x16x32_bf16((A),(B),(C),0,0,0)

__global__ __launch_bounds__(TPB) void lstm_mfma(
    const float* __restrict__ x,      // [4096,256,32]
    const float* __restrict__ W_ih1,  // [256,32]
    const float* __restrict__ W_hh1,  // [256,64]
    const float* __restrict__ b_ih1,  // [256]
    const float* __restrict__ b_hh1,  // [256]
    const float* __restrict__ W_ih2,  // [128,64]
    const float* __restrict__ W_hh2,  // [128,32]
    const float* __restrict__ b_ih2,  // [128]
    const float* __restrict__ b_hh2,  // [128]
    const float* __restrict__ W_fc1,  // [16,32]
    const float* __restrict__ b_fc1,  // [16]
    const float* __restrict__ W_fc2,  // [1,16]
    const float* __restrict__ b_fc2,  // [1]
    float* __restrict__ out)          // [4096]
{
    const int tid  = threadIdx.x;
    const int lane = tid & 63;
    const int wid  = tid >> 6;        // 0..15
    const int bb   = lane & 15;       // fragment col / batch
    const int kg   = (lane >> 4) & 3; // k-group of 8
    const int b0   = blockIdx.x * NBB;

    // img1 = [x(32)|h1(64)], img2 = [h1(64)|h2(32)]; hi/lo bf16, double-buffered
    __shared__ __align__(16) unsigned short i1h[2][NBB][IMW], i1l[2][NBB][IMW];
    __shared__ __align__(16) unsigned short i2h[2][NBB][IMW], i2l[2][NBB][IMW];
    __shared__ __align__(16) float pre1[NBB * PR1];   // L1 preacts [batch][row 0..255]
    __shared__ __align__(16) float pre2[NBB * PR2];   // L2 preacts [batch][row 0..127]
    __shared__ float hfin[NBB][32];
    __shared__ float hd[NBB][16];

    // ============ weight fragments: uniform 16-row tiles ============
    // wave wid -> L1 tile rows [16*wid, 16*wid+16); waves 0-7 also L2 tile rows [16*wid, ..)
    const int R1 = 16 * wid;
    bf16x8 w1h[3], w1l[3];
    f32x4  bfr;
    {
        const int r = R1 + bb;
        make_frags(&W_ih1[r*32 +      8*kg], w1h[0], w1l[0]);
        make_frags(&W_hh1[r*64 +      8*kg], w1h[1], w1l[1]);
        make_frags(&W_hh1[r*64 + 32 + 8*kg], w1h[2], w1l[2]);
        #pragma unroll
        for (int q = 0; q < 4; ++q){
            const int row = R1 + 4*kg + q;
            bfr[q] = b_ih1[row] + b_hh1[row];
        }
    }
    bf16x8 w2h[3], w2l[3];
    if (wid < 8){
        const int r = R1 + bb;   // R1 = 16*wid, wid<8 -> rows 0..127
        make_frags(&W_ih2[r*64 +      8*kg], w2h[0], w2l[0]);
        make_frags(&W_ih2[r*64 + 32 + 8*kg], w2h[1], w2l[1]);
        make_frags(&W_hh2[r*32 +      8*kg], w2h[2], w2l[2]);
    }

    // combine ownership
    const int u1c = tid >> 4;          // 0..63 (all 1024 threads: one L1 unit-batch)
    const int b1c = tid & 15;
    const int u2c = (tid >> 4) & 31;   // for tid<512: L2 unit
    float bias2[4];
    #pragma unroll
    for (int g = 0; g < 4; ++g) bias2[g] = b_ih2[u2c + 32*g] + b_hh2[u2c + 32*g];

    // x staging owned by light waves (tid >= 512): 512 threads = 16 b x 32 f
    const int xs  = tid & 511;
    const int xbb = xs >> 5, xff = xs & 31;
    const size_t xbase = (size_t)(b0 + xbb) * (T_*F_) + xff;

    // ============ init: zero images, stage x(0) ============
    for (int i = tid; i < NBB*IMW; i += TPB){
        ((unsigned*)i1h)[i] = 0u; ((unsigned*)i1l)[i] = 0u;
        ((unsigned*)i2h)[i] = 0u; ((unsigned*)i2l)[i] = 0u;
    }
    float xn = 0.f;
    __syncthreads();
    if (tid >= 512){
        unsigned short h, l; bf16_split(x[xbase], h, l);
        i1h[0][xbb][xff] = h; i1l[0][xbb][xff] = l;
        xn = x[xbase + F_];
    }
    __syncthreads();

    float c1 = 0.f, c2 = 0.f;

    // ============ main loop: L2 lags L1 by one step ============
    for (int t = 0; t <= T_; ++t){
        const int cur = t & 1, nxt = cur ^ 1;

        // ---- phase 1: MFMA -> preact LDS ----
        if (t < T_){
            const unsigned short* ph = &i1h[cur][0][0] + bb*IMW + 8*kg;
            const unsigned short* pl = &i1l[cur][0][0] + bb*IMW + 8*kg;
            bf16x8 vh[3], vl[3];
            #pragma unroll
            for (int kb = 0; kb < 3; ++kb){
                vh[kb] = *(const bf16x8*)(ph + 32*kb);
                vl[kb] = *(const bf16x8*)(pl + 32*kb);
            }
            f32x4 a0 = bfr, a1 = {0.f,0.f,0.f,0.f};
            a0 = MFMA(w1h[0], vh[0], a0);  a0 = MFMA(w1h[0], vl[0], a0);
            a1 = MFMA(w1l[0], vh[0], a1);  a1 = MFMA(w1h[1], vl[1], a1);
            a0 = MFMA(w1h[1], vh[1], a0);  a1 = MFMA(w1l[1], vh[1], a1);
            a0 = MFMA(w1h[2], vh[2], a0);  a0 = MFMA(w1h[2], vl[2], a0);
            a1 = MFMA(w1l[2], vh[2], a1);
            const f32x4 s = a0 + a1;
            *(f32x4*)&pre1[bb*PR1 + R1 + 4*kg] = s;
        }
        if (wid < 8 && t > 0){
            const unsigned short* ph = &i2h[cur][0][0] + bb*IMW + 8*kg;
            const unsigned short* pl = &i2l[cur][0][0] + bb*IMW + 8*kg;
            bf16x8 vh[3], vl[3];
            #pragma unroll
            for (int kb = 0; kb < 3; ++kb){
                vh[kb] = *(const bf16x8*)(ph + 32*kb);
                vl[kb] = *(const bf16x8*)(pl + 32*kb);
            }
            f32x4 a0 = {0.f,0.f,0.f,0.f}, a1 = {0.f,0.f,0.f,0.f};
            a0 = MFMA(w2h[0], vh[0], a0);  a0 = MFMA(w2h[0], vl[0], a0);
            a1 = MFMA(w2l[0], vh[0], a1);  a1 = MFMA(w2h[1], vl[1], a1);
            a0 = MFMA(w2h[1], vh[1], a0);  a1 = MFMA(w2l[1], vh[1], a1);
            a0 = MFMA(w2h[2], vh[2], a0);  a0 = MFMA(w2h[2], vl[2], a0);
            a1 = MFMA(w2l[2], vh[2], a1);
            const f32x4 s = a0 + a1;
            *(f32x4*)&pre2[bb*PR2 + R1 + 4*kg] = s;
        }
        __syncthreads();

        // ---- phase 2: combine + write img[nxt] ----
        if (t < T_){
            const float gi = pre1[b1c*PR1 +       u1c];
            const float gf = pre1[b1c*PR1 +  64 + u1c];
            const float gg = pre1[b1c*PR1 + 128 + u1c];
            const float go = pre1[b1c*PR1 + 192 + u1c];
            const float i_ = sigmoid_fast(gi);
            const float f_ = sigmoid_fast(gf);
            const float g_ = tanh_fast   (gg);
            const float o_ = sigmoid_fast(go);
            c1 = fmaf(f_, c1, i_ * g_);
            const float h1v = o_ * tanh_fast(c1);
            unsigned short h, l; bf16_split(h1v, h, l);
            i1h[nxt][b1c][32 + u1c] = h;  i1l[nxt][b1c][32 + u1c] = l;
            i2h[nxt][b1c][u1c]      = h;  i2l[nxt][b1c][u1c]      = l;
        }
        if (tid < 512 && t > 0){
            const float g0 = pre2[b1c*PR2 + u2c      ] + bias2[0];
            const float g1 = pre2[b1c*PR2 + u2c + 32 ] + bias2[1];
            const float g2 = pre2[b1c*PR2 + u2c + 64 ] + bias2[2];
            const float g3 = pre2[b1c*PR2 + u2c + 96 ] + bias2[3];
            const float i_ = sigmoid_fast(g0);
            const float f_ = sigmoid_fast(g1);
            const float gg = tanh_fast   (g2);
            const float o_ = sigmoid_fast(g3);
            c2 = fmaf(f_, c2, i_ * gg);
            const float h2v = o_ * tanh_fast(c2);
            unsigned short h, l; bf16_split(h2v, h, l);
            i2h[nxt][b1c][64 + u2c] = h;  i2l[nxt][b1c][64 + u2c] = l;
            if (t == T_) hfin[b1c][u2c] = h2v;
        }
        if (tid >= 512 && t < T_ - 1){
            unsigned short h, l; bf16_split(xn, h, l);
            i1h[nxt][xbb][xff] = h;  i1l[nxt][xbb][xff] = l;
            const int tn = (t + 2 < T_) ? t + 2 : T_ - 1;
            xn = x[xbase + (size_t)tn * F_];
        }
        __syncthreads();
    }

    // ============ head ============
    if (tid < NBB * 16){
        const int b = tid >> 4, j2 = tid & 15;
        float a = b_fc1[j2];
        #pragma unroll
        for (int k = 0; k < 32; ++k) a = fmaf(W_fc1[j2*32 + k], hfin[b][k], a);
        hd[b][j2] = fmaxf(a, 0.f);
    }
    __syncthreads();
    if (tid < NBB){
        float a = b_fc2[0];
        #pragma unroll
        for (int k = 0; k < 16; ++k) a = fmaf(W_fc2[k], hd[tid][k], a);
        out[b0 + tid] = a;
    }
}

extern "C" void kernel_launch(void* const* d_in, const int* in_sizes, int n_in,
                              void* d_out, int out_size, void* d_ws, size_t ws_size,
                              hipStream_t stream) {
    const float* x     = (const float*)d_in[0];
    const float* W_ih1 = (const float*)d_in[1];
    const float* W_hh1 = (const float*)d_in[2];
    const float* b_ih1 = (const float*)d_in[3];
    const float* b_hh1 = (const float*)d_in[4];
    const float* W_ih2 = (const float*)d_in[5];
    const float* W_hh2 = (const float*)d_in[6];
    const float* b_ih2 = (const float*)d_in[7];
    const float* b_hh2 = (const float*)d_in[8];
    const float* W_fc1 = (const float*)d_in[9];
    const float* b_fc1 = (const float*)d_in[10];
    const float* W_fc2 = (const float*)d_in[11];
    const float* b_fc2 = (const float*)d_in[12];
    float* out = (float*)d_out;

    const int B = in_sizes[0] / (T_ * F_);   // 4096
    dim3 grid(B / NBB), block(TPB);          // 256 blocks, 1024 threads
    hipLaunchKernelGGL(lstm_mfma, grid, block, 0, stream,
                       x, W_ih1, W_hh1, b_ih1, b_hh1,
                       W_ih2, W_hh2, b_ih2, b_hh2,
                       W_fc1, b_fc1, W_fc2, b_fc2, out);
}

// Round 6
// 486.213 us; speedup vs baseline: 1.0166x; 1.0166x over previous
//
#include <hip/hip_runtime.h>

#define T_   256
#define F_   32
#define NBB  16     // batch elements per block
#define TPB  512    // 8 waves: 4 L1, 2 L2, 2 X-staging
#define IMW  104    // img row width in ushorts

typedef __attribute__((ext_vector_type(8))) short bf16x8;
typedef __attribute__((ext_vector_type(4))) float f32x4;
typedef __attribute__((ext_vector_type(4))) unsigned short ush4;

__device__ __forceinline__ float sigmoid_fast(float x){ return __fdividef(1.f, 1.f + __expf(-x)); }
__device__ __forceinline__ float tanh_fast(float x){ float e = __expf(2.f*x); return 1.f - __fdividef(2.f, e + 1.f); }

__device__ __forceinline__ unsigned short bf16_rne(float x){
    unsigned u = __float_as_uint(x);
    u += 0x7FFF + ((u >> 16) & 1);
    return (unsigned short)(u >> 16);
}
__device__ __forceinline__ void bf16_split(float x, unsigned short& h, unsigned short& l){
    h = bf16_rne(x);
    float xr = __uint_as_float(((unsigned)h) << 16);
    l = bf16_rne(x - xr);
}
__device__ __forceinline__ void make_frags(const float* __restrict__ p8, bf16x8& fh, bf16x8& fl){
    #pragma unroll
    for (int e = 0; e < 8; ++e){
        unsigned short h, l; bf16_split(p8[e], h, l);
        fh[e] = (short)h; fl[e] = (short)l;
    }
}

#define MFMA(A,B,C) __builtin_amdgcn_mfma_f32_16x16x32_bf16((A),(B),(C),0,0,0)

// launch_bounds(512,2): min 2 waves/EU = exactly our 8-wave block -> 256-VGPR cap.
// (512,4) would cap at 128 and spill the ~96 weight-fragment VGPRs (round-2 lesson).
__global__ __launch_bounds__(TPB, 2) void lstm_mfma(
    const float* __restrict__ x,      // [4096,256,32]
    const float* __restrict__ W_ih1,  // [256,32]
    const float* __restrict__ W_hh1,  // [256,64]
    const float* __restrict__ b_ih1,  // [256]
    const float* __restrict__ b_hh1,  // [256]
    const float* __restrict__ W_ih2,  // [128,64]
    const float* __restrict__ W_hh2,  // [128,32]
    const float* __restrict__ b_ih2,  // [128]
    const float* __restrict__ b_hh2,  // [128]
    const float* __restrict__ W_fc1,  // [16,32]
    const float* __restrict__ b_fc1,  // [16]
    const float* __restrict__ W_fc2,  // [1,16]
    const float* __restrict__ b_fc2,  // [1]
    float* __restrict__ out)          // [4096]
{
    const int tid  = threadIdx.x;
    const int lane = tid & 63;
    const int wid  = tid >> 6;        // 0..7
    const int bb   = lane & 15;       // fragment col = batch
    const int kg   = (lane >> 4) & 3; // k-group of 8
    const int b0   = blockIdx.x * NBB;

    // img1 = [x(32)|h1(64)], img2 = [h1(64)|h2(32)]; hi/lo bf16, double-buffered
    __shared__ __align__(16) unsigned short i1h[2][NBB][IMW], i1l[2][NBB][IMW];
    __shared__ __align__(16) unsigned short i2h[2][NBB][IMW], i2l[2][NBB][IMW];
    __shared__ float hfin[NBB][32];
    __shared__ float hd[NBB][16];

    // ===== role-specific state =====
    bf16x8 wh[4][3], wl[4][3];   // 4 gate tiles x 3 k-blocks (L1 or L2 role)
    f32x4  bfr[4];               // per-gate bias (rows 4kg..4kg+3 of tile)
    float  cc[4] = {0.f,0.f,0.f,0.f};  // c1 (L1) or c2 (L2) for 4 owned units
    int    uo = 0;               // owned-unit base offset

    if (wid < 4){
        // L1: wave owns units 16*wid..+15, ALL 4 gates (gate-colocated)
        uo = 16*wid + 4*kg;
        #pragma unroll
        for (int g = 0; g < 4; ++g){
            const int r = 64*g + 16*wid + bb;
            make_frags(&W_ih1[r*32 +      8*kg], wh[g][0], wl[g][0]);
            make_frags(&W_hh1[r*64 +      8*kg], wh[g][1], wl[g][1]);
            make_frags(&W_hh1[r*64 + 32 + 8*kg], wh[g][2], wl[g][2]);
            #pragma unroll
            for (int q = 0; q < 4; ++q){
                const int row = 64*g + 16*wid + 4*kg + q;
                bfr[g][q] = b_ih1[row] + b_hh1[row];
            }
        }
    } else if (wid < 6){
        // L2: wave j owns units 16*j..+15, ALL 4 gates
        const int j = wid - 4;
        uo = 16*j + 4*kg;
        #pragma unroll
        for (int g = 0; g < 4; ++g){
            const int r = 32*g + 16*j + bb;
            make_frags(&W_ih2[r*64 +      8*kg], wh[g][0], wl[g][0]);
            make_frags(&W_ih2[r*64 + 32 + 8*kg], wh[g][1], wl[g][1]);
            make_frags(&W_hh2[r*32 +      8*kg], wh[g][2], wl[g][2]);
            #pragma unroll
            for (int q = 0; q < 4; ++q){
                const int row = 32*g + 16*j + 4*kg + q;
                bfr[g][q] = b_ih2[row] + b_hh2[row];
            }
        }
    }

    // X-staging state (waves 6,7 = 128 threads; 4 elems each of the 512-elem slab)
    const int xs = tid - 384;
    int xb_[4], xf_[4];
    size_t xbase[4];
    float xc[4];
    if (wid >= 6){
        #pragma unroll
        for (int j = 0; j < 4; ++j){
            const int e = xs + 128*j;
            xb_[j] = e >> 5; xf_[j] = e & 31;
            xbase[j] = (size_t)(b0 + xb_[j]) * (T_*F_) + xf_[j];
        }
    }

    // ===== init: zero images (h regions must be 0), stage x(0), preload x(1) =====
    for (int i = tid; i < 2*NBB*IMW; i += TPB){
        (&i1h[0][0][0])[i] = 0; (&i1l[0][0][0])[i] = 0;
        (&i2h[0][0][0])[i] = 0; (&i2l[0][0][0])[i] = 0;
    }
    __syncthreads();
    if (wid >= 6){
        #pragma unroll
        for (int j = 0; j < 4; ++j){
            unsigned short h, l; bf16_split(x[xbase[j]], h, l);
            i1h[0][xb_[j]][xf_[j]] = h; i1l[0][xb_[j]][xf_[j]] = l;
            xc[j] = x[xbase[j] + F_];
        }
    }
    __syncthreads();

    // ===== main loop: ONE barrier per step; L2 lags L1 by one step =====
    for (int t = 0; t <= T_; ++t){
        const int cur = t & 1, nxt = cur ^ 1;

        if (wid < 4){
            if (t < T_){
                const unsigned short* ph = &i1h[cur][0][0] + bb*IMW + 8*kg;
                const unsigned short* pl = &i1l[cur][0][0] + bb*IMW + 8*kg;
                bf16x8 vh[3], vl[3];
                #pragma unroll
                for (int kb = 0; kb < 3; ++kb){
                    vh[kb] = *(const bf16x8*)(ph + 32*kb);
                    vl[kb] = *(const bf16x8*)(pl + 32*kb);
                }
                f32x4 A0[4], A1[4];
                #pragma unroll
                for (int g = 0; g < 4; ++g){ A0[g] = bfr[g]; A1[g] = {0.f,0.f,0.f,0.f}; }
                // 9 MFMA/gate (hh x3, lh x3, hl x3), two chains depth 4/5, 8-way ILP
                #pragma unroll
                for (int kb = 0; kb < 3; ++kb)
                    #pragma unroll
                    for (int g = 0; g < 4; ++g) A0[g] = MFMA(wh[g][kb], vh[kb], A0[g]);
                #pragma unroll
                for (int kb = 0; kb < 3; ++kb)
                    #pragma unroll
                    for (int g = 0; g < 4; ++g) A1[g] = MFMA(wl[g][kb], vh[kb], A1[g]);
                #pragma unroll
                for (int g = 0; g < 4; ++g) A0[g] = MFMA(wh[g][0], vl[0], A0[g]);
                #pragma unroll
                for (int g = 0; g < 4; ++g){
                    A1[g] = MFMA(wh[g][1], vl[1], A1[g]);
                    A1[g] = MFMA(wh[g][2], vl[2], A1[g]);
                }
                // in-register combine: lane owns units uo..uo+3 of batch bb
                ush4 HH, HL;
                #pragma unroll
                for (int q = 0; q < 4; ++q){
                    const float i_ = sigmoid_fast(A0[0][q] + A1[0][q]);
                    const float f_ = sigmoid_fast(A0[1][q] + A1[1][q]);
                    const float g_ = tanh_fast   (A0[2][q] + A1[2][q]);
                    const float o_ = sigmoid_fast(A0[3][q] + A1[3][q]);
                    cc[q] = fmaf(f_, cc[q], i_ * g_);
                    const float h1v = o_ * tanh_fast(cc[q]);
                    unsigned short h, l; bf16_split(h1v, h, l);
                    HH[q] = h; HL[q] = l;
                }
                *(ush4*)&i1h[nxt][bb][32 + uo] = HH;
                *(ush4*)&i1l[nxt][bb][32 + uo] = HL;
                *(ush4*)&i2h[nxt][bb][uo]      = HH;
                *(ush4*)&i2l[nxt][bb][uo]      = HL;
            }
        } else if (wid < 6){
            if (t > 0){   // computes h2(t-1)
                const unsigned short* ph = &i2h[cur][0][0] + bb*IMW + 8*kg;
                const unsigned short* pl = &i2l[cur][0][0] + bb*IMW + 8*kg;
                bf16x8 vh[3], vl[3];
                #pragma unroll
                for (int kb = 0; kb < 3; ++kb){
                    vh[kb] = *(const bf16x8*)(ph + 32*kb);
                    vl[kb] = *(const bf16x8*)(pl + 32*kb);
                }
                f32x4 A0[4], A1[4];
                #pragma unroll
                for (int g = 0; g < 4; ++g){ A0[g] = bfr[g]; A1[g] = {0.f,0.f,0.f,0.f}; }
                #pragma unroll
                for (int kb = 0; kb < 3; ++kb)
                    #pragma unroll
                    for (int g = 0; g < 4; ++g) A0[g] = MFMA(wh[g][kb], vh[kb], A0[g]);
                #pragma unroll
                for (int kb = 0; kb < 3; ++kb)
                    #pragma unroll
                    for (int g = 0; g < 4; ++g) A1[g] = MFMA(wl[g][kb], vh[kb], A1[g]);
                #pragma unroll
                for (int g = 0; g < 4; ++g) A0[g] = MFMA(wh[g][0], vl[0], A0[g]);
                #pragma unroll
                for (int g = 0; g < 4; ++g){
                    A1[g] = MFMA(wh[g][1], vl[1], A1[g]);
                    A1[g] = MFMA(wh[g][2], vl[2], A1[g]);
                }
                ush4 HH, HL;
                f32x4 hv;
                #pragma unroll
                for (int q = 0; q < 4; ++q){
                    const float i_ = sigmoid_fast(A0[0][q] + A1[0][q]);
                    const float f_ = sigmoid_fast(A0[1][q] + A1[1][q]);
                    const float g_ = tanh_fast   (A0[2][q] + A1[2][q]);
                    const float o_ = sigmoid_fast(A0[3][q] + A1[3][q]);
                    cc[q] = fmaf(f_, cc[q], i_ * g_);
                    const float h2v = o_ * tanh_fast(cc[q]);
                    unsigned short h, l; bf16_split(h2v, h, l);
                    HH[q] = h; HL[q] = l; hv[q] = h2v;
                }
                *(ush4*)&i2h[nxt][bb][64 + uo] = HH;
                *(ush4*)&i2l[nxt][bb][64 + uo] = HL;
                if (t == T_) *(f32x4*)&hfin[bb][uo] = hv;
            }
        } else {
            if (t < T_ - 1){
                // stage x(t+1) from regs; then issue loads of x(t+2) (drain waits
                // at OUR barrier arrival only -- MFMA waves never see it)
                #pragma unroll
                for (int j = 0; j < 4; ++j){
                    unsigned short h, l; bf16_split(xc[j], h, l);
                    i1h[nxt][xb_[j]][xf_[j]] = h;
                    i1l[nxt][xb_[j]][xf_[j]] = l;
                }
                const int tn = (t + 2 < T_) ? t + 2 : T_ - 1;
                #pragma unroll
                for (int j = 0; j < 4; ++j) xc[j] = x[xbase[j] + (size_t)tn * F_];
            }
        }
        __syncthreads();
    }

    // ===== head: fc1(16)+relu, fc2(1) =====
    if (tid < NBB * 16){
        const int b = tid >> 4, j2 = tid & 15;
        float a = b_fc1[j2];
        #pragma unroll
        for (int k = 0; k < 32; ++k) a = fmaf(W_fc1[j2*32 + k], hfin[b][k], a);
        hd[b][j2] = fmaxf(a, 0.f);
    }
    __syncthreads();
    if (tid < NBB){
        float a = b_fc2[0];
        #pragma unroll
        for (int k = 0; k < 16; ++k) a = fmaf(W_fc2[k], hd[tid][k], a);
        out[b0 + tid] = a;
    }
}

extern "C" void kernel_launch(void* const* d_in, const int* in_sizes, int n_in,
                              void* d_out, int out_size, void* d_ws, size_t ws_size,
                              hipStream_t stream) {
    const float* x     = (const float*)d_in[0];
    const float* W_ih1 = (const float*)d_in[1];
    const float* W_hh1 = (const float*)d_in[2];
    const float* b_ih1 = (const float*)d_in[3];
    const float* b_hh1 = (const float*)d_in[4];
    const float* W_ih2 = (const float*)d_in[5];
    const float* W_hh2 = (const float*)d_in[6];
    const float* b_ih2 = (const float*)d_in[7];
    const float* b_hh2 = (const float*)d_in[8];
    const float* W_fc1 = (const float*)d_in[9];
    const float* b_fc1 = (const float*)d_in[10];
    const float* W_fc2 = (const float*)d_in[11];
    const float* b_fc2 = (const float*)d_in[12];
    float* out = (float*)d_out;

    const int B = in_sizes[0] / (T_ * F_);   // 4096
    dim3 grid(B / NBB), block(TPB);          // 256 blocks, 1/CU
    hipLaunchKernelGGL(lstm_mfma, grid, block, 0, stream,
                       x, W_ih1, W_hh1, b_ih1, b_hh1,
                       W_ih2, W_hh2, b_ih2, b_hh2,
                       W_fc1, b_fc1, W_fc2, b_fc2, out);
}